// Round 8
// baseline (234.696 us; speedup 1.0000x reference)
//
#include <hip/hip_runtime.h>
#include <math.h>

#define T_SEQ  1024
#define C_DIM  1024
#define NH_    16
#define H_DIM  64
#define SCL    (0.125f * 1.4426950408889634f)   // 1/sqrt(64) folded with log2e

typedef __bf16 bf16;
typedef __bf16 bf16x4 __attribute__((ext_vector_type(4)));
typedef __bf16 bf16x8 __attribute__((ext_vector_type(8)));
typedef short  s16x4  __attribute__((ext_vector_type(4)));
typedef float  f32x4  __attribute__((ext_vector_type(4)));

#define MFMA16(a, b, c)  __builtin_amdgcn_mfma_f32_16x16x32_bf16(a, b, c, 0, 0, 0)
#define MFMAK16(a, b, c) __builtin_amdgcn_mfma_f32_16x16x16bf16_1k(a, b, c, 0, 0, 0)

#define GLOAD_LDS16(g, l) __builtin_amdgcn_global_load_lds( \
    (const __attribute__((address_space(1))) void*)(g),     \
    (__attribute__((address_space(3))) void*)(l), 16, 0, 0)

__device__ __forceinline__ bf16x8 neg8(bf16x8 x) {
    union { bf16x8 v; unsigned int u[4]; } t;
    t.v = x;
    t.u[0] ^= 0x80008000u; t.u[1] ^= 0x80008000u;
    t.u[2] ^= 0x80008000u; t.u[3] ^= 0x80008000u;
    return t.v;
}

// fragment read from XOR-8-chunk-swizzled [rows][64] bf16 plane
__device__ __forceinline__ bf16x8 frag_sw(const bf16* plane, int row, int chunk) {
    int c = chunk ^ (row & 7);
    return *(const bf16x8*)&plane[row * 64 + c * 8];
}

// ---------------------------------------------------------------------------
// splits: fp32 complex [R][1024][2] -> bf16 planes (re, im), 8 complex/thread.
// z==5 builds the RoPE phasor table.
// ---------------------------------------------------------------------------
__global__ __launch_bounds__(256)
void split_all(const float* __restrict__ x,  const float* __restrict__ wq,
               const float* __restrict__ wk, const float* __restrict__ wv,
               const float* __restrict__ wo,
               bf16* Xr, bf16* Xi, bf16* Wqr, bf16* Wqi, bf16* Wkr, bf16* Wki,
               bf16* Wvr, bf16* Wvi, bf16* Wor, bf16* Woi,
               float* __restrict__ rope)
{
    int z = blockIdx.y;
    if (z == 5) {
        if (blockIdx.x >= 256) return;
        int idx = blockIdx.x * 256 + threadIdx.x;   // 65536
        int tp = idx >> 6, d = idx & 63;
        float invf = exp2f((float)d * -0.2076205059304601f);
        float fr = (float)tp * invf;
        float sn, cs; sincosf(fr, &sn, &cs);
        *(float2*)&rope[(size_t)idx * 2] = make_float2(cs, sn);
        return;
    }
    if (z > 0 && blockIdx.x >= 512) return;
    const float* in; bf16 *pr, *pi;
    if      (z == 0) { in = x;  pr = Xr;  pi = Xi;  }
    else if (z == 1) { in = wq; pr = Wqr; pi = Wqi; }
    else if (z == 2) { in = wk; pr = Wkr; pi = Wki; }
    else if (z == 3) { in = wv; pr = Wvr; pi = Wvi; }
    else             { in = wo; pr = Wor; pi = Woi; }
    int idx = (blockIdx.x * 256 + threadIdx.x) * 8;   // 8 complex per thread
    bf16x8 r, im;
#pragma unroll
    for (int j = 0; j < 4; j++) {
        float4 v = *(const float4*)(in + (size_t)idx * 2 + j * 4);
        r[2*j]   = (bf16)v.x; im[2*j]   = (bf16)v.y;
        r[2*j+1] = (bf16)v.z; im[2*j+1] = (bf16)v.w;
    }
    *(bf16x8*)(pr + idx) = r;
    *(bf16x8*)(pi + idx) = im;
}

// ---------------------------------------------------------------------------
// 128x64 complex GEMM core, BK=64. smem passed in (single shared alloc).
// mode 1: q/k planes [B,H,T,64] + RoPE (phasor scaled by qscale).
// mode 2: v planes transposed [B,H,64,T].
// ---------------------------------------------------------------------------
__device__ __forceinline__ void cgemm128(
    bf16* __restrict__ smem,
    const bf16* __restrict__ Ar, const bf16* __restrict__ Ai,
    const bf16* __restrict__ Br, const bf16* __restrict__ Bi,
    const float* __restrict__ bias, const float* __restrict__ rope,
    bf16* __restrict__ Yr, bf16* __restrict__ Yi, int m0, int n0, int mode,
    float qscale)
{
    const int t = threadIdx.x, lane = t & 63, wave = t >> 6;
    const int wm = (wave >> 1) * 64, wn = (wave & 1) * 32;
    const int lm = lane & 15, quad = lane >> 4;
    const int s_lr = lane >> 3, s_c = (lane & 7) ^ s_lr;

    f32x4 accr[4][2], acci[4][2];
#pragma unroll
    for (int i = 0; i < 4; i++)
#pragma unroll
        for (int j = 0; j < 2; j++) { accr[i][j] = (f32x4)0.f; acci[i][j] = (f32x4)0.f; }

    for (int k0 = 0; k0 < C_DIM; k0 += 64) {
#pragma unroll
        for (int j = 0; j < 12; j++) {
            int c = wave + 4 * j;
            const bf16* src; bf16* dst;
            if (c < 16)      {             src = Ar + (size_t)(m0 + c * 8 + s_lr) * C_DIM + k0 + s_c * 8; dst = smem + c * 512; }
            else if (c < 32) { int u = c - 16; src = Ai + (size_t)(m0 + u * 8 + s_lr) * C_DIM + k0 + s_c * 8; dst = smem + 8192 + u * 512; }
            else if (c < 40) { int u = c - 32; src = Br + (size_t)(n0 + u * 8 + s_lr) * C_DIM + k0 + s_c * 8; dst = smem + 16384 + u * 512; }
            else             { int u = c - 40; src = Bi + (size_t)(n0 + u * 8 + s_lr) * C_DIM + k0 + s_c * 8; dst = smem + 20480 + u * 512; }
            GLOAD_LDS16(src, dst);
        }
        __syncthreads();

#pragma unroll
        for (int kh = 0; kh < 2; kh++) {
            bf16x8 ar[4], ai_[4], br_[2], bi_[2], bn_[2];
#pragma unroll
            for (int i = 0; i < 4; i++) {
                ar[i]  = frag_sw(smem,        wm + i * 16 + lm, kh * 4 + quad);
                ai_[i] = frag_sw(smem + 8192, wm + i * 16 + lm, kh * 4 + quad);
            }
#pragma unroll
            for (int j = 0; j < 2; j++) {
                br_[j] = frag_sw(smem + 16384, wn + j * 16 + lm, kh * 4 + quad);
                bi_[j] = frag_sw(smem + 20480, wn + j * 16 + lm, kh * 4 + quad);
                bn_[j] = neg8(bi_[j]);
            }
#pragma unroll
            for (int i = 0; i < 4; i++)
#pragma unroll
                for (int j = 0; j < 2; j++) {
                    accr[i][j] = MFMA16(ar[i],  br_[j], accr[i][j]);
                    accr[i][j] = MFMA16(ai_[i], bn_[j], accr[i][j]);
                    acci[i][j] = MFMA16(ar[i],  bi_[j], acci[i][j]);
                    acci[i][j] = MFMA16(ai_[i], br_[j], acci[i][j]);
                }
        }
        __syncthreads();
    }

    const int h = n0 >> 6, bb = m0 >> 10, tbase = m0 & (T_SEQ - 1);

    if (mode == 1) {
#pragma unroll
        for (int i = 0; i < 4; i++)
#pragma unroll
            for (int j = 0; j < 2; j++) {
                int d = wn + j * 16 + lm;
                float2 bv = *(const float2*)&bias[2 * (n0 + d)];
#pragma unroll
                for (int r = 0; r < 4; r++) {
                    int tpos = tbase + wm + i * 16 + quad * 4 + r;
                    float2 ph = *(const float2*)&rope[((size_t)tpos * H_DIM + d) * 2];
                    float px = ph.x * qscale, py = ph.y * qscale;
                    float yr = accr[i][j][r] + bv.x;
                    float yi = acci[i][j][r] + bv.y;
                    accr[i][j][r] = yr * px - yi * py;
                    acci[i][j][r] = yr * py + yi * px;
                }
            }
        bf16* dsts[2] = { Yr, Yi };
#pragma unroll
        for (int pass = 0; pass < 2; pass++) {
            __syncthreads();
#pragma unroll
            for (int i = 0; i < 4; i++)
#pragma unroll
                for (int j = 0; j < 2; j++)
#pragma unroll
                    for (int r = 0; r < 4; r++)
                        smem[(wm + i * 16 + quad * 4 + r) * 72 + wn + j * 16 + lm] =
                            (bf16)(pass ? acci[i][j][r] : accr[i][j][r]);
            __syncthreads();
            bf16* dst = dsts[pass] + ((size_t)(bb * NH_ + h) * T_SEQ + tbase) * H_DIM;
#pragma unroll
            for (int p = 0; p < 4; p++) {
                int ch = t + 256 * p;
                int row = ch >> 3, o = (ch & 7) * 8;
                *(bf16x8*)&dst[row * H_DIM + o] = *(const bf16x8*)&smem[row * 72 + o];
            }
        }
    } else {
        bf16* dsts[2] = { Yr, Yi };
#pragma unroll
        for (int pass = 0; pass < 2; pass++) {
            __syncthreads();
#pragma unroll
            for (int i = 0; i < 4; i++)
#pragma unroll
                for (int j = 0; j < 2; j++) {
                    int d = wn + j * 16 + lm;
                    float2 bv = *(const float2*)&bias[2 * (n0 + d)];
                    float bb2 = pass ? bv.y : bv.x;
                    bf16x4 pk;
#pragma unroll
                    for (int r = 0; r < 4; r++)
                        pk[r] = (bf16)((pass ? acci[i][j][r] : accr[i][j][r]) + bb2);
                    *(bf16x4*)&smem[d * 136 + wm + i * 16 + quad * 4] = pk;
                }
            __syncthreads();
            bf16* dst = dsts[pass] + ((size_t)(bb * NH_ + h) * H_DIM) * T_SEQ + tbase;
#pragma unroll
            for (int p = 0; p < 4; p++) {
                int ch = t + 256 * p;
                int row = ch >> 4, o = (ch & 15) * 8;
                *(bf16x8*)&dst[(size_t)row * T_SEQ + o] = *(const bf16x8*)&smem[row * 136 + o];
            }
        }
    }
}

__global__ __launch_bounds__(256, 3)
void qkv_gemm(const bf16* __restrict__ Xr, const bf16* __restrict__ Xi,
              const bf16* __restrict__ Wqr, const bf16* __restrict__ Wqi,
              const bf16* __restrict__ Wkr, const bf16* __restrict__ Wki,
              const bf16* __restrict__ Wvr, const bf16* __restrict__ Wvi,
              const float* __restrict__ bq, const float* __restrict__ bk,
              const float* __restrict__ bv, const float* __restrict__ rope,
              bf16* Qr, bf16* Qi, bf16* Kr, bf16* Ki, bf16* Vr, bf16* Vi)
{
    __shared__ __attribute__((aligned(16))) bf16 smem[24576];  // ONE 48 KB alloc
    int m0 = blockIdx.y * 128, n0 = blockIdx.x * 64;
    const bf16 *Br, *Bi; const float* bias; bf16 *Yr, *Yi; int mode; float qs;
    if (blockIdx.z == 0)      { Br = Wqr; Bi = Wqi; bias = bq; Yr = Qr; Yi = Qi; mode = 1; qs = SCL;  }
    else if (blockIdx.z == 1) { Br = Wkr; Bi = Wki; bias = bk; Yr = Kr; Yi = Ki; mode = 1; qs = 1.0f; }
    else                      { Br = Wvr; Bi = Wvi; bias = bv; Yr = Vr; Yi = Vi; mode = 2; qs = 1.0f; }
    cgemm128(smem, Xr, Xi, Br, Bi, bias, rope, Yr, Yi, m0, n0, mode, qs);
}

// ---------------------------------------------------------------------------
// 64x64 complex GEMM, BK=64 (final projection, fp32 interleaved out).
// ---------------------------------------------------------------------------
__global__ __launch_bounds__(256, 4)
void out_gemm(const bf16* __restrict__ Ar, const bf16* __restrict__ Ai,
              const bf16* __restrict__ Br, const bf16* __restrict__ Bi,
              const float* __restrict__ bias, float* __restrict__ Y)
{
    __shared__ __attribute__((aligned(16))) bf16 sm[16384];   // 32 KB
    const int t = threadIdx.x, lane = t & 63, wave = t >> 6;
    const int lm = lane & 15, quad = lane >> 4;
    const int s_lr = lane >> 3, s_c = (lane & 7) ^ s_lr;
    const int wm = (wave >> 1) * 32, wn = (wave & 1) * 32;
    const int m0 = blockIdx.y * 64, n0 = blockIdx.x * 64;

    f32x4 accr[2][2], acci[2][2];
#pragma unroll
    for (int i = 0; i < 2; i++)
#pragma unroll
        for (int j = 0; j < 2; j++) { accr[i][j] = (f32x4)0.f; acci[i][j] = (f32x4)0.f; }

    for (int k0 = 0; k0 < C_DIM; k0 += 64) {
#pragma unroll
        for (int j = 0; j < 8; j++) {
            int c = wave + 4 * j;
            const bf16* src; bf16* dst;
            if (c < 8)       {             src = Ar + (size_t)(m0 + c * 8 + s_lr) * C_DIM + k0 + s_c * 8; dst = sm + c * 512; }
            else if (c < 16) { int u = c - 8;  src = Ai + (size_t)(m0 + u * 8 + s_lr) * C_DIM + k0 + s_c * 8; dst = sm + 4096 + u * 512; }
            else if (c < 24) { int u = c - 16; src = Br + (size_t)(n0 + u * 8 + s_lr) * C_DIM + k0 + s_c * 8; dst = sm + 8192 + u * 512; }
            else             { int u = c - 24; src = Bi + (size_t)(n0 + u * 8 + s_lr) * C_DIM + k0 + s_c * 8; dst = sm + 12288 + u * 512; }
            GLOAD_LDS16(src, dst);
        }
        __syncthreads();
#pragma unroll
        for (int kh = 0; kh < 2; kh++) {
            bf16x8 ar[2], ai_[2], br_[2], bi_[2], bn_[2];
#pragma unroll
            for (int i = 0; i < 2; i++) {
                ar[i]  = frag_sw(sm,        wm + i * 16 + lm, kh * 4 + quad);
                ai_[i] = frag_sw(sm + 4096, wm + i * 16 + lm, kh * 4 + quad);
            }
#pragma unroll
            for (int j = 0; j < 2; j++) {
                br_[j] = frag_sw(sm + 8192,  wn + j * 16 + lm, kh * 4 + quad);
                bi_[j] = frag_sw(sm + 12288, wn + j * 16 + lm, kh * 4 + quad);
                bn_[j] = neg8(bi_[j]);
            }
#pragma unroll
            for (int i = 0; i < 2; i++)
#pragma unroll
                for (int j = 0; j < 2; j++) {
                    accr[i][j] = MFMA16(ar[i],  br_[j], accr[i][j]);
                    accr[i][j] = MFMA16(ai_[i], bn_[j], accr[i][j]);
                    acci[i][j] = MFMA16(ar[i],  bi_[j], acci[i][j]);
                    acci[i][j] = MFMA16(ai_[i], br_[j], acci[i][j]);
                }
        }
        __syncthreads();
    }
#pragma unroll
    for (int i = 0; i < 2; i++)
#pragma unroll
        for (int j = 0; j < 2; j++) {
            int n = n0 + wn + j * 16 + lm;
            float2 bv = *(const float2*)&bias[2 * n];
#pragma unroll
            for (int r = 0; r < 4; r++) {
                int m = m0 + wm + i * 16 + quad * 4 + r;
                *(float2*)&Y[((size_t)m * C_DIM + n) * 2] =
                    make_float2(accr[i][j][r] + bv.x, acci[i][j][r] + bv.y);
            }
        }
}

// ---------------------------------------------------------------------------
// MFMA flash attention v4: 256-thread blocks (2 qg x 2 sh waves), 32 q-rows,
// 16-s double-buffered tiles (one barrier/iter), 1024 blocks -> 5 blocks/CU.
// Score C-layout == K=16 A-layout identity: P transpose is FREE (no bpermute).
// Q pre-scaled by SCL in qkv_gemm, so p = exp2(|s|) directly.
// LDS 32 KB: buf0 [0,8192), buf1 [8192,16384) elems; per buf per sh 4096:
//   Kr[0,1024) Ki[1024,2048) Vr[2048,3072) Vi[3072,4096).
// Q (2 planes x 32x64 = 4096 elems) aliased into buf1 pre-loop.
// ---------------------------------------------------------------------------
__global__ __launch_bounds__(256, 5)
void attn_mfma(const bf16* __restrict__ Qpr, const bf16* __restrict__ Qpi,
               const bf16* __restrict__ Kpr, const bf16* __restrict__ Kpi,
               const bf16* __restrict__ Vtr, const bf16* __restrict__ Vti,
               bf16* __restrict__ ABr, bf16* __restrict__ ABi)
{
    __shared__ __attribute__((aligned(16))) bf16 smem[16384];  // 32 KB
    const int t = threadIdx.x, lane = t & 63, wv = t >> 6;
    const int qg = wv & 1, sh = wv >> 1;
    const int lm = lane & 15, quad = lane >> 4;
    const int q0 = blockIdx.x * 32;
    const int h = blockIdx.y, b = blockIdx.z;
    const size_t hb = (size_t)(b * NH_ + h) * T_SEQ * H_DIM;
    const int s_lr = lane >> 3, s_c = (lane & 7) ^ s_lr;

    // ---- stage Q (2 planes x 32 rows x 64) into buf1 first 4096 elems ----
#pragma unroll
    for (int j = 0; j < 2; j++) {
        int u = wv * 2 + j;                    // 8 units of 8 rows
        const bf16* gq = ((u >> 2) ? Qpi : Qpr) + hb + (size_t)q0 * H_DIM;
        GLOAD_LDS16(gq + ((u & 3) * 8 + s_lr) * H_DIM + s_c * 8,
                    smem + 8192 + (u >> 2) * 2048 + (u & 3) * 512);
    }
    __syncthreads();
    bf16x8 qfr[2], qfi[2], nqfr[2];
#pragma unroll
    for (int kh = 0; kh < 2; kh++) {
        qfr[kh]  = frag_sw(smem + 8192,  qg * 16 + lm, kh * 4 + quad);
        qfi[kh]  = frag_sw(smem + 10240, qg * 16 + lm, kh * 4 + quad);
        nqfr[kh] = neg8(qfr[kh]);
    }

    // ---- per-wave staging: wave (qg,sh) stages 2 planes of its sh tile ----
    // qg==0: Kr,Ki ([16 s][64 d], 8-row chunks, XOR-8 swizzled cols)
    // qg==1: Vr,Vi ([64 d][16 s], 32-row chunks, plain)
    const bf16 *g0, *g1; size_t cstride; int gstep, dof0, dof1;
    if (qg == 0) {
        size_t off = hb + (size_t)(sh * 512) * H_DIM + (size_t)s_lr * H_DIM + s_c * 8;
        g0 = Kpr + off; g1 = Kpi + off;
        cstride = (size_t)8 * H_DIM; gstep = 16 * H_DIM;
        dof0 = sh * 4096; dof1 = sh * 4096 + 1024;
    } else {
        size_t off = hb + (size_t)(sh * 512) + (size_t)(lane >> 1) * T_SEQ + (lane & 1) * 8;
        g0 = Vtr + off; g1 = Vti + off;
        cstride = (size_t)32 * T_SEQ; gstep = 16;
        dof0 = sh * 4096 + 2048; dof1 = sh * 4096 + 3072;
    }
    // prefetch tile 0 into buf0
#pragma unroll
    for (int cc = 0; cc < 2; cc++) {
        GLOAD_LDS16(g0 + cc * cstride, smem + dof0 + cc * 512);
        GLOAD_LDS16(g1 + cc * cstride, smem + dof1 + cc * 512);
    }

    f32x4 Or[4], Oi[4];
#pragma unroll
    for (int nt = 0; nt < 4; nt++) { Or[nt] = (f32x4)0.f; Oi[nt] = (f32x4)0.f; }
    float lsum = 0.f;

    for (int it = 0; it < 32; it++) {
        __syncthreads();   // drains stage(it) (vmcnt0) + prior buf readers
        if (it < 31) {     // stage tile it+1 into the other buffer
            const bf16* s0 = g0 + (size_t)(it + 1) * gstep;
            const bf16* s1 = g1 + (size_t)(it + 1) * gstep;
            bf16* d = smem + ((it + 1) & 1) * 8192;
#pragma unroll
            for (int cc = 0; cc < 2; cc++) {
                GLOAD_LDS16(s0 + cc * cstride, d + dof0 + cc * 512);
                GLOAD_LDS16(s1 + cc * cstride, d + dof1 + cc * 512);
            }
        }
        const bf16* buf = smem + (it & 1) * 8192 + sh * 4096;

        // ---- S^T scores over 16-s tile: lane holds (q=lm, s=quad*4+r) ----
        f32x4 sre = (f32x4)0.f, sim = (f32x4)0.f;
#pragma unroll
        for (int kh = 0; kh < 2; kh++) {
            bf16x8 kr = frag_sw(buf,        lm, kh * 4 + quad);
            bf16x8 ki = frag_sw(buf + 1024, lm, kh * 4 + quad);
            sre = MFMA16(kr, qfr[kh],  sre);
            sre = MFMA16(ki, qfi[kh],  sre);
            sim = MFMA16(kr, qfi[kh],  sim);
            sim = MFMA16(ki, nqfr[kh], sim);
        }
        union { s16x4 s; bf16x4 b; } pf;
#pragma unroll
        for (int r = 0; r < 4; r++) {
            float p = exp2f(sqrtf(sre[r] * sre[r] + sim[r] * sim[r]));
            lsum += p;
            pf.b[r] = (bf16)p;
        }

        // ---- PV via K=16 MFMA: A = P (identity layout), B = V[s][d] ----
        const bf16* vr = buf + 2048;
        const bf16* vi = buf + 3072;
#pragma unroll
        for (int nt = 0; nt < 4; nt++) {
            s16x4 vfr = *(const s16x4*)&vr[(nt * 16 + lm) * 16 + quad * 4];
            s16x4 vfi = *(const s16x4*)&vi[(nt * 16 + lm) * 16 + quad * 4];
            Or[nt] = MFMAK16(pf.s, vfr, Or[nt]);
            Oi[nt] = MFMAK16(pf.s, vfi, Oi[nt]);
        }
    }

    // ---- lsum: per-lane (q=lm) partial over quads -> full sh-half sum ----
    lsum += __shfl_xor(lsum, 16);
    lsum += __shfl_xor(lsum, 32);

    // ---- merge sh halves via LDS ----
    float* Of = (float*)smem;          // 64 rows (2 planes x 32 q) x 64 fp32
    float* fm = Of + 4096;             // 32 floats
    __syncthreads();
    if (sh == 1) {
#pragma unroll
        for (int nt = 0; nt < 4; nt++)
#pragma unroll
            for (int r = 0; r < 4; r++) {
                Of[(qg * 16 + quad * 4 + r) * 64 + nt * 16 + lm]        = Or[nt][r];
                Of[(32 + qg * 16 + quad * 4 + r) * 64 + nt * 16 + lm]   = Oi[nt][r];
            }
        if (quad == 0) fm[qg * 16 + lm] = lsum;
    }
    __syncthreads();
    if (sh == 0) {
        float lv = 1.f / (lsum + fm[qg * 16 + lm]);
        float linv[4];
#pragma unroll
        for (int r = 0; r < 4; r++)
            linv[r] = __shfl(lv, (quad << 4) + quad * 4 + r, 64);
        size_t mbase = (size_t)(b * T_SEQ + q0 + qg * 16 + quad * 4) * C_DIM;
        int colb = h * H_DIM + lm;
#pragma unroll
        for (int nt = 0; nt < 4; nt++)
#pragma unroll
            for (int r = 0; r < 4; r++) {
                float orv = Or[nt][r] + Of[(qg * 16 + quad * 4 + r) * 64 + nt * 16 + lm];
                float oiv = Oi[nt][r] + Of[(32 + qg * 16 + quad * 4 + r) * 64 + nt * 16 + lm];
                size_t o = mbase + (size_t)r * C_DIM + colb + nt * 16;
                ABr[o] = (bf16)(orv * linv[r]);
                ABi[o] = (bf16)(oiv * linv[r]);
            }
    }
}

// ---------------------------------------------------------------------------
extern "C" void kernel_launch(void* const* d_in, const int* in_sizes, int n_in,
                              void* d_out, int out_size, void* d_ws, size_t ws_size,
                              hipStream_t stream) {
    const float* x  = (const float*)d_in[0];
    const float* wq = (const float*)d_in[1];
    const float* bq = (const float*)d_in[2];
    const float* wk = (const float*)d_in[3];
    const float* bk = (const float*)d_in[4];
    const float* wv = (const float*)d_in[5];
    const float* bv = (const float*)d_in[6];
    const float* wo = (const float*)d_in[7];
    const float* bo = (const float*)d_in[8];

    float* rope = (float*)d_ws;                       // 131072 floats (512 KB)
    bf16* w = (bf16*)(rope + 131072);
    const size_t MSZ = (size_t)2048 * 1024;
    const size_t WSZ = (size_t)1024 * 1024;
    const size_t PSZ = (size_t)2 * NH_ * T_SEQ * H_DIM;

    bf16 *Xr = w, *Xi = Xr + MSZ;
    bf16 *Wqr = Xi + MSZ,  *Wqi = Wqr + WSZ;
    bf16 *Wkr = Wqi + WSZ, *Wki = Wkr + WSZ;
    bf16 *Wvr = Wki + WSZ, *Wvi = Wvr + WSZ;
    bf16 *Wor = Wvi + WSZ, *Woi = Wor + WSZ;
    bf16 *Qr = Woi + WSZ, *Qi = Qr + PSZ;
    bf16 *Kr = Qi + PSZ,  *Ki = Kr + PSZ;
    bf16 *Vr = Ki + PSZ,  *Vi = Vr + PSZ;
    bf16 *ABr = Vi + PSZ, *ABi = ABr + MSZ;

    split_all<<<dim3(1024, 6), 256, 0, stream>>>(x, wq, wk, wv, wo,
        Xr, Xi, Wqr, Wqi, Wkr, Wki, Wvr, Wvi, Wor, Woi, rope);

    qkv_gemm<<<dim3(16, 16, 3), 256, 0, stream>>>(
        Xr, Xi, Wqr, Wqi, Wkr, Wki, Wvr, Wvi, bq, bk, bv, rope,
        Qr, Qi, Kr, Ki, Vr, Vi);

    attn_mfma<<<dim3(32, 16, 2), 256, 0, stream>>>(
        Qr, Qi, Kr, Ki, Vr, Vi, ABr, ABi);

    out_gemm<<<dim3(16, 32), 256, 0, stream>>>(ABr, ABi, Wor, Woi, bo, (float*)d_out);
}